// Round 2
// baseline (500.539 us; speedup 1.0000x reference)
//
#include <hip/hip_runtime.h>
#include <hip/hip_fp16.h>
#include <hip/hip_cooperative_groups.h>

namespace cg = cooperative_groups;

// Problem: B=8192, L=64, M=64, LOCAL_DIM=4, eps shape (4, 64, 64, 65, 65) f32.
// out[b] = sum_m prod_l eps[idx[b,l], m, l, nup[b,l], ndn[b,l]]
// nup/ndn = exclusive cumsum of bit0/bit1 of idx along l.
//
// eps element strides: d:17305600, m:270400, l:4225, u:65, n:1
// Compact transposed table (reachable u<=l, n<=l states), fp16:
//   tab[(P_l + u*(l+1) + n)*256 + d*64 + m],  P_l = l(l+1)(2l+1)/6
// fp16 accuracy: eps ~[0.7,1.3]; product-of-64 rel err ~2.3e-3; absmax 0.5
// observed vs 1.56 threshold.
//
// R4: only transpose states actually VISITED (per-l [umin,umax]x[nmin,nmax]
// pre-pass). ~3.5x less transpose traffic.
// R5: main = 4 batches/wave, ushort4 gathers, packed-index shuffle.
// R6 (this round): whole chain fused into ONE cooperative persistent kernel
// (512 blocks x 256 thr, 2 blocks/CU) with grid.sync between phases:
//   A) init + ranges via __ballot/popcount (replaces 12-shuffle scan)
//   B) persistent-loop transpose of visited states
//   C) R5 main body (block k == old blockIdx k)
// Removes 3 launch gaps + scan cost. Falls back to the proven 4-kernel
// path if cooperative launch is rejected (e.g. under graph capture).

#define TAB_HALF_BYTES ((size_t)89440 * 256 * 2)

// ---------------- fused cooperative kernel ----------------
__global__ __launch_bounds__(256, 2) void seggps_fused(
    const int* __restrict__ indices, const float* __restrict__ eps,
    __half* __restrict__ tab, int* __restrict__ ranges,
    float* __restrict__ out) {
  cg::grid_group grid = cg::this_grid();
  __shared__ float tile[64][65];        // transpose tile [m][n]
  __shared__ int s_umin[64], s_umax[64], s_nmin[64], s_nmax[64];

  int t = threadIdx.x;
  int wave = t >> 6, lane = t & 63;
  int blk = blockIdx.x;                 // grid = 512

  // ---- Phase A0: init global ranges (block 0) + local LDS init ----
  if (blk == 0 && t < 64) {
    ranges[t] = 64;        // umin
    ranges[64 + t] = -1;   // umax
    ranges[128 + t] = 64;  // nmin
    ranges[192 + t] = -1;  // nmax
  }
  if (t < 64) { s_umin[t] = 64; s_umax[t] = -1; s_nmin[t] = 64; s_nmax[t] = -1; }
  grid.sync();

  // ---- Phase A1: ranges over this block's 16 batches, ballot-based ----
  {
    unsigned long long ltmask =
        (lane == 63) ? 0x7fffffffffffffffull : ((1ull << lane) - 1ull);
    for (int i = 0; i < 4; ++i) {       // 4 batches per wave
      int b = blk * 16 + wave * 4 + i;
      int v = indices[b * 64 + lane];   // lane = l
      unsigned long long m0 = __ballot(v & 1);
      unsigned long long m1 = __ballot(v & 2);
      int eu = __popcll(m0 & ltmask);   // exclusive n_up at site lane
      int ed = __popcll(m1 & ltmask);   // exclusive n_dn
      atomicMin(&s_umin[lane], eu); atomicMax(&s_umax[lane], eu);
      atomicMin(&s_nmin[lane], ed); atomicMax(&s_nmax[lane], ed);
    }
    __syncthreads();
    if (t < 64) {
      atomicMin(&ranges[t], s_umin[t]);
      atomicMax(&ranges[64 + t], s_umax[t]);
      atomicMin(&ranges[128 + t], s_nmin[t]);
      atomicMax(&ranges[192 + t], s_nmax[t]);
    }
  }
  grid.sync();

  // ---- Phase B: transpose visited states (persistent loop) ----
  for (int item = blk; item < 4 * 2080; item += 512) {
    int d = item / 2080;
    int tt = item % 2080;
    int l = (int)((sqrtf(8.0f * (float)tt + 1.0f) - 1.0f) * 0.5f);
    while ((l + 1) * (l + 2) / 2 <= tt) ++l;   // fix fp rounding
    while (l * (l + 1) / 2 > tt) --l;
    int u = tt - l * (l + 1) / 2;

    int umin = ranges[l], umax = ranges[64 + l];
    if (u < umin || u > umax) continue;        // block-uniform branch
    int nmin = ranges[128 + l], nmax = ranges[192 + l];

    // load: coalesced along n (stride 1 in eps); plain loads so row-boundary
    // cache lines shared between adjacent u can hit L2
    const float* src = eps + ((size_t)(d * 64) * 64 + l) * 4225 + u * 65;
    if (lane >= nmin && lane <= nmax) {
#pragma unroll 4
      for (int m = wave; m < 64; m += 4) {
        tile[m][lane] = src[(size_t)m * 270400 + lane];
      }
    }
    __syncthreads();

    // store: coalesced along m (128B contiguous per wave)
    int Pl = l * (l + 1) * (2 * l + 1) / 6;
    __half* dst = tab + (size_t)(Pl + u * (l + 1)) * 256 + d * 64 + lane;
    for (int n = nmin + wave; n <= nmax; n += 4) {
      dst[n * 256] = __float2half(tile[lane][n]);
    }
    __syncthreads();                           // tile reused next item
  }
  grid.sync();

  // ---- Phase C: main (R5 body; block k == old blockIdx k) ----
  {
    int g = lane >> 4;                  // batch subgroup 0..3
    int Lm = lane & 15;                 // m-quad index
    int b0 = (blk * 4 + wave) * 4;      // this wave handles b0 .. b0+3

    int ipk = indices[(b0 + 0) * 64 + lane]
            | (indices[(b0 + 1) * 64 + lane] << 2)
            | (indices[(b0 + 2) * 64 + lane] << 4)
            | (indices[(b0 + 3) * 64 + lane] << 6);

    float p0 = 1.f, p1 = 1.f, p2 = 1.f, p3 = 1.f;
    int up = 0, dn = 0;
    int Pl = 0;
    int mbase = Lm * 4;
#pragma unroll 16
    for (int l = 0; l < 64; ++l) {
      int s = __shfl(ipk, l, 64);
      int v = (s >> (2 * g)) & 3;
      int o = (Pl + up * (l + 1) + dn) * 256 + v * 64 + mbase;
      ushort4 q = *reinterpret_cast<const ushort4*>(tab + o);  // 8B aligned
      p0 *= __half2float(__ushort_as_half(q.x));
      p1 *= __half2float(__ushort_as_half(q.y));
      p2 *= __half2float(__ushort_as_half(q.z));
      p3 *= __half2float(__ushort_as_half(q.w));
      up += v & 1;
      dn += (v >> 1) & 1;
      Pl += (l + 1) * (l + 1);
    }
    float r = (p0 + p1) + (p2 + p3);
#pragma unroll
    for (int s2 = 8; s2; s2 >>= 1) r += __shfl_down(r, s2, 16);
    if (Lm == 0) out[b0 + g] = r;
  }
}

// ---------------- fallback 4-kernel path (proven, R5) ----------------
__global__ __launch_bounds__(256) void seggps_init(int* __restrict__ ranges) {
  int t = threadIdx.x;
  if (t < 64) {
    ranges[t] = 64;
    ranges[64 + t] = -1;
    ranges[128 + t] = 64;
    ranges[192 + t] = -1;
  }
}

__global__ __launch_bounds__(256) void seggps_ranges(
    const int* __restrict__ indices, int* __restrict__ ranges) {
  __shared__ int s_umin[64], s_umax[64], s_nmin[64], s_nmax[64];
  int t = threadIdx.x;
  if (t < 64) { s_umin[t] = 64; s_umax[t] = -1; s_nmin[t] = 64; s_nmax[t] = -1; }
  __syncthreads();
  int wave = t >> 6, lane = t & 63;
  unsigned long long ltmask =
      (lane == 63) ? 0x7fffffffffffffffull : ((1ull << lane) - 1ull);
  for (int i = 0; i < 16; ++i) {
    int b = blockIdx.x * 64 + wave * 16 + i;
    int v = indices[b * 64 + lane];
    unsigned long long m0 = __ballot(v & 1);
    unsigned long long m1 = __ballot(v & 2);
    int eu = __popcll(m0 & ltmask);
    int ed = __popcll(m1 & ltmask);
    atomicMin(&s_umin[lane], eu); atomicMax(&s_umax[lane], eu);
    atomicMin(&s_nmin[lane], ed); atomicMax(&s_nmax[lane], ed);
  }
  __syncthreads();
  if (t < 64) {
    atomicMin(&ranges[t], s_umin[t]);
    atomicMax(&ranges[64 + t], s_umax[t]);
    atomicMin(&ranges[128 + t], s_nmin[t]);
    atomicMax(&ranges[192 + t], s_nmax[t]);
  }
}

__global__ __launch_bounds__(256) void seggps_transpose(
    const float* __restrict__ eps, __half* __restrict__ tab,
    const int* __restrict__ ranges) {
  int bid = blockIdx.x;
  int d = bid / 2080;
  int tt = bid % 2080;
  int l = (int)((sqrtf(8.0f * (float)tt + 1.0f) - 1.0f) * 0.5f);
  while ((l + 1) * (l + 2) / 2 <= tt) ++l;
  while (l * (l + 1) / 2 > tt) --l;
  int u = tt - l * (l + 1) / 2;

  int umin = ranges[l], umax = ranges[64 + l];
  if (u < umin || u > umax) return;
  int nmin = ranges[128 + l], nmax = ranges[192 + l];

  int lane = threadIdx.x & 63;
  int wave = threadIdx.x >> 6;

  __shared__ float tile[64][65];

  const float* src = eps + ((size_t)(d * 64) * 64 + l) * 4225 + u * 65;
  if (lane >= nmin && lane <= nmax) {
#pragma unroll 4
    for (int m = wave; m < 64; m += 4) {
      tile[m][lane] = src[(size_t)m * 270400 + lane];
    }
  }
  __syncthreads();

  int Pl = l * (l + 1) * (2 * l + 1) / 6;
  __half* dst = tab + (size_t)(Pl + u * (l + 1)) * 256 + d * 64 + lane;
  for (int n = nmin + wave; n <= nmax; n += 4) {
    dst[n * 256] = __float2half(tile[lane][n]);
  }
}

__global__ __launch_bounds__(256, 4) void seggps_main(
    const int* __restrict__ indices, const __half* __restrict__ tab,
    float* __restrict__ out) {
  int wave = threadIdx.x >> 6;
  int lane = threadIdx.x & 63;
  int g = lane >> 4;
  int Lm = lane & 15;
  int b0 = (blockIdx.x * 4 + wave) * 4;

  int ipk = indices[(b0 + 0) * 64 + lane]
          | (indices[(b0 + 1) * 64 + lane] << 2)
          | (indices[(b0 + 2) * 64 + lane] << 4)
          | (indices[(b0 + 3) * 64 + lane] << 6);

  float p0 = 1.f, p1 = 1.f, p2 = 1.f, p3 = 1.f;
  int up = 0, dn = 0;
  int Pl = 0;
  int mbase = Lm * 4;
#pragma unroll 16
  for (int l = 0; l < 64; ++l) {
    int s = __shfl(ipk, l, 64);
    int v = (s >> (2 * g)) & 3;
    int o = (Pl + up * (l + 1) + dn) * 256 + v * 64 + mbase;
    ushort4 q = *reinterpret_cast<const ushort4*>(tab + o);
    p0 *= __half2float(__ushort_as_half(q.x));
    p1 *= __half2float(__ushort_as_half(q.y));
    p2 *= __half2float(__ushort_as_half(q.z));
    p3 *= __half2float(__ushort_as_half(q.w));
    up += v & 1;
    dn += (v >> 1) & 1;
    Pl += (l + 1) * (l + 1);
  }
  float r = (p0 + p1) + (p2 + p3);
#pragma unroll
  for (int s2 = 8; s2; s2 >>= 1) r += __shfl_down(r, s2, 16);
  if (Lm == 0) out[b0 + g] = r;
}

// Fallback if workspace is too small: gather straight from eps.
__global__ __launch_bounds__(256) void seggps_direct(
    const int* __restrict__ indices, const float* __restrict__ eps,
    float* __restrict__ out) {
  int wave = threadIdx.x >> 6;
  int lane = threadIdx.x & 63;
  int b = blockIdx.x * 4 + wave;

  int myidx = indices[b * 64 + lane];

  float p0 = 1.f, p1 = 1.f, p2 = 1.f, p3 = 1.f;
  int up = 0, dn = 0;
#pragma unroll 8
  for (int l = 0; l < 64; ++l) {
    int v = __shfl(myidx, l, 64);
    size_t off = ((size_t)((v * 64 + lane) * 64 + l)) * 4225 + up * 65 + dn;
    float e = eps[off];
    if ((l & 3) == 0)      p0 *= e;
    else if ((l & 3) == 1) p1 *= e;
    else if ((l & 3) == 2) p2 *= e;
    else                   p3 *= e;
    up += v & 1;
    dn += (v >> 1) & 1;
  }
  float p = (p0 * p1) * (p2 * p3);
#pragma unroll
  for (int s = 32; s; s >>= 1) p += __shfl_down(p, s, 64);
  if (lane == 0) out[b] = p;
}

extern "C" void kernel_launch(void* const* d_in, const int* in_sizes, int n_in,
                              void* d_out, int out_size, void* d_ws, size_t ws_size,
                              hipStream_t stream) {
  const int* indices = (const int*)d_in[0];   // (8192, 64) int
  const float* eps   = (const float*)d_in[1]; // (4, 64, 64, 65, 65) f32
  float* out = (float*)d_out;                 // (8192,) f32

  if (ws_size >= TAB_HALF_BYTES + 1024) {
    __half* tab = (__half*)d_ws;
    int* ranges = (int*)((char*)d_ws + TAB_HALF_BYTES);  // 256 ints

    void* args[] = {(void*)&indices, (void*)&eps, (void*)&tab,
                    (void*)&ranges, (void*)&out};
    hipError_t e = hipLaunchCooperativeKernel(
        (const void*)seggps_fused, dim3(512), dim3(256), args, 0, stream);
    if (e != hipSuccess) {
      (void)hipGetLastError();  // clear; fall back to proven 4-kernel path
      hipLaunchKernelGGL(seggps_init, dim3(1), dim3(256), 0, stream, ranges);
      hipLaunchKernelGGL(seggps_ranges, dim3(128), dim3(256), 0, stream,
                         indices, ranges);
      hipLaunchKernelGGL(seggps_transpose, dim3(4 * 2080), dim3(256), 0, stream,
                         eps, tab, ranges);
      hipLaunchKernelGGL(seggps_main, dim3(8192 / 16), dim3(256), 0, stream,
                         indices, tab, out);
    }
  } else {
    hipLaunchKernelGGL(seggps_direct, dim3(8192 / 4), dim3(256), 0, stream,
                       indices, eps, out);
  }
}

// Round 3
// 335.890 us; speedup vs baseline: 1.4902x; 1.4902x over previous
//
#include <hip/hip_runtime.h>
#include <hip/hip_fp16.h>

// Problem: B=8192, L=64, M=64, LOCAL_DIM=4, eps shape (4, 64, 64, 65, 65) f32.
// out[b] = sum_m prod_l eps[idx[b,l], m, l, nup[b,l], ndn[b,l]]
// nup/ndn = exclusive cumsum of bit0/bit1 of idx along l.
//
// eps element strides: d:17305600, m:270400, l:4225, u:65, n:1
// Compact transposed table (reachable u<=l, n<=l states), fp16:
//   tab[(P_l + u*(l+1) + n)*256 + d*64 + m],  P_l = l(l+1)(2l+1)/6
// fp16 accuracy: eps ~[0.7,1.3]; product-of-64 rel err ~2.3e-3; absmax 0.5
// observed vs 1.56 threshold.
//
// R4: only transpose states actually VISITED (per-l [umin,umax]x[nmin,nmax]
// pre-pass). ~3.5x less transpose traffic.
// R5: main = 4 batches/wave, ushort4 gathers, packed-index shuffle. (341.8us)
// R6: FAILED - cooperative fusion serialized the transpose (512 blocks x 16
//     serial items, 202us alone; total 500us). Launch gaps were never the
//     cost; block-level parallelism in the transpose was. Reverted.
// R7 (this round): proven 4-kernel chain + ballot/popcount ranges
//     (2 ops vs 12 shuffles per batch). Chain memory floor ~9.5us
//     (FETCH 46MB + WRITE 14MB measured in R6); harness reset (1.08GB
//     poison fill @83% peak = 166us + input restore) dominates total.

#define TAB_HALF_BYTES ((size_t)89440 * 256 * 2)

__global__ __launch_bounds__(256) void seggps_init(int* __restrict__ ranges) {
  int t = threadIdx.x;
  if (t < 64) {
    ranges[t] = 64;        // umin
    ranges[64 + t] = -1;   // umax
    ranges[128 + t] = 64;  // nmin
    ranges[192 + t] = -1;  // nmax
  }
}

// grid = 128 blocks x 256 thr; block handles 64 batches. Ballot+popcount
// gives each batch's exclusive (u,n) at every site; LDS min/max then 256
// global atomics.
__global__ __launch_bounds__(256) void seggps_ranges(
    const int* __restrict__ indices, int* __restrict__ ranges) {
  __shared__ int s_umin[64], s_umax[64], s_nmin[64], s_nmax[64];
  int t = threadIdx.x;
  if (t < 64) { s_umin[t] = 64; s_umax[t] = -1; s_nmin[t] = 64; s_nmax[t] = -1; }
  __syncthreads();
  int wave = t >> 6, lane = t & 63;    // lane = l
  unsigned long long ltmask =
      (lane == 63) ? 0x7fffffffffffffffull : ((1ull << lane) - 1ull);
  for (int i = 0; i < 16; ++i) {
    int b = blockIdx.x * 64 + wave * 16 + i;
    int v = indices[b * 64 + lane];
    unsigned long long m0 = __ballot(v & 1);   // bit l set iff site l has up
    unsigned long long m1 = __ballot(v & 2);
    int eu = __popcll(m0 & ltmask);            // exclusive cumsum at site lane
    int ed = __popcll(m1 & ltmask);
    atomicMin(&s_umin[lane], eu); atomicMax(&s_umax[lane], eu);
    atomicMin(&s_nmin[lane], ed); atomicMax(&s_nmax[lane], ed);
  }
  __syncthreads();
  if (t < 64) {
    atomicMin(&ranges[t], s_umin[t]);
    atomicMax(&ranges[64 + t], s_umax[t]);
    atomicMin(&ranges[128 + t], s_nmin[t]);
    atomicMax(&ranges[192 + t], s_nmax[t]);
  }
}

__global__ __launch_bounds__(256) void seggps_transpose(
    const float* __restrict__ eps, __half* __restrict__ tab,
    const int* __restrict__ ranges) {
  int bid = blockIdx.x;                 // grid = 4 * 2080 (triangular)
  int d = bid / 2080;
  int t = bid % 2080;
  int l = (int)((sqrtf(8.0f * (float)t + 1.0f) - 1.0f) * 0.5f);
  while ((l + 1) * (l + 2) / 2 <= t) ++l;   // fix fp rounding
  while (l * (l + 1) / 2 > t) --l;
  int u = t - l * (l + 1) / 2;

  int umin = ranges[l], umax = ranges[64 + l];
  if (u < umin || u > umax) return;     // no batch visits this u at site l
  int nmin = ranges[128 + l], nmax = ranges[192 + l];  // nmax <= l always

  int lane = threadIdx.x & 63;          // n on load, m on store
  int wave = threadIdx.x >> 6;          // 4 waves

  __shared__ float tile[64][65];        // [m][n]

  // load: coalesced along n (stride 1 in eps); nontemporal (no reuse,
  // eps = 277MB > L3)
  const float* src = eps + ((size_t)(d * 64) * 64 + l) * 4225 + u * 65;
  if (lane >= nmin && lane <= nmax) {
#pragma unroll 4
    for (int m = wave; m < 64; m += 4) {
      tile[m][lane] = __builtin_nontemporal_load(&src[(size_t)m * 270400 + lane]);
    }
  }
  __syncthreads();

  // store: coalesced along m (128B contiguous per wave)
  int Pl = l * (l + 1) * (2 * l + 1) / 6;
  __half* dst = tab + (size_t)(Pl + u * (l + 1)) * 256 + d * 64 + lane;
  for (int n = nmin + wave; n <= nmax; n += 4) {
    dst[n * 256] = __float2half(tile[lane][n]);
  }
}

// R5 main: 4 batches per wave. Lane layout: g = lane>>4 selects the batch,
// Lm = lane&15 selects an m-quad (m = 4*Lm .. 4*Lm+3, ushort4 = 8B load,
// 16 lanes x 8B = one 128B line per batch-group per site). Indices of the
// 4 batches are packed 2 bits each into one int -> one __shfl per site.
__global__ __launch_bounds__(256, 4) void seggps_main(
    const int* __restrict__ indices, const __half* __restrict__ tab,
    float* __restrict__ out) {
  int wave = threadIdx.x >> 6;
  int lane = threadIdx.x & 63;
  int g = lane >> 4;                    // batch subgroup 0..3
  int Lm = lane & 15;                   // m-quad index
  int b0 = (blockIdx.x * 4 + wave) * 4; // this wave handles b0 .. b0+3

  int ipk = indices[(b0 + 0) * 64 + lane]
          | (indices[(b0 + 1) * 64 + lane] << 2)
          | (indices[(b0 + 2) * 64 + lane] << 4)
          | (indices[(b0 + 3) * 64 + lane] << 6);

  float p0 = 1.f, p1 = 1.f, p2 = 1.f, p3 = 1.f;
  int up = 0, dn = 0;                   // this lane's batch's counters
  int Pl = 0;                           // l(l+1)(2l+1)/6, built incrementally
  int mbase = Lm * 4;
#pragma unroll 16
  for (int l = 0; l < 64; ++l) {
    int s = __shfl(ipk, l, 64);
    int v = (s >> (2 * g)) & 3;
    int o = (Pl + up * (l + 1) + dn) * 256 + v * 64 + mbase;
    ushort4 q = *reinterpret_cast<const ushort4*>(tab + o);  // 8B, aligned
    p0 *= __half2float(__ushort_as_half(q.x));
    p1 *= __half2float(__ushort_as_half(q.y));
    p2 *= __half2float(__ushort_as_half(q.z));
    p3 *= __half2float(__ushort_as_half(q.w));
    up += v & 1;
    dn += (v >> 1) & 1;
    Pl += (l + 1) * (l + 1);
  }
  // p0..p3 are products for four DIFFERENT m -> sum, then reduce over the
  // 16-lane group (width=16 keeps the shuffle inside the group).
  float r = (p0 + p1) + (p2 + p3);
#pragma unroll
  for (int s = 8; s; s >>= 1) r += __shfl_down(r, s, 16);
  if (Lm == 0) out[b0 + g] = r;
}

// Fallback if workspace is too small: gather straight from eps.
__global__ __launch_bounds__(256) void seggps_direct(
    const int* __restrict__ indices, const float* __restrict__ eps,
    float* __restrict__ out) {
  int wave = threadIdx.x >> 6;
  int lane = threadIdx.x & 63;          // lane = m
  int b = blockIdx.x * 4 + wave;

  int myidx = indices[b * 64 + lane];

  float p0 = 1.f, p1 = 1.f, p2 = 1.f, p3 = 1.f;
  int up = 0, dn = 0;
#pragma unroll 8
  for (int l = 0; l < 64; ++l) {
    int v = __shfl(myidx, l, 64);
    size_t off = ((size_t)((v * 64 + lane) * 64 + l)) * 4225 + up * 65 + dn;
    float e = eps[off];
    if ((l & 3) == 0)      p0 *= e;
    else if ((l & 3) == 1) p1 *= e;
    else if ((l & 3) == 2) p2 *= e;
    else                   p3 *= e;
    up += v & 1;
    dn += (v >> 1) & 1;
  }
  float p = (p0 * p1) * (p2 * p3);
#pragma unroll
  for (int s = 32; s; s >>= 1) p += __shfl_down(p, s, 64);
  if (lane == 0) out[b] = p;
}

extern "C" void kernel_launch(void* const* d_in, const int* in_sizes, int n_in,
                              void* d_out, int out_size, void* d_ws, size_t ws_size,
                              hipStream_t stream) {
  const int* indices = (const int*)d_in[0];   // (8192, 64) int
  const float* eps   = (const float*)d_in[1]; // (4, 64, 64, 65, 65) f32
  float* out = (float*)d_out;                 // (8192,) f32

  if (ws_size >= TAB_HALF_BYTES + 1024) {
    __half* tab = (__half*)d_ws;
    int* ranges = (int*)((char*)d_ws + TAB_HALF_BYTES);  // 256 ints
    hipLaunchKernelGGL(seggps_init, dim3(1), dim3(256), 0, stream, ranges);
    hipLaunchKernelGGL(seggps_ranges, dim3(128), dim3(256), 0, stream,
                       indices, ranges);
    hipLaunchKernelGGL(seggps_transpose, dim3(4 * 2080), dim3(256), 0, stream,
                       eps, tab, ranges);
    hipLaunchKernelGGL(seggps_main, dim3(8192 / 16), dim3(256), 0, stream,
                       indices, tab, out);
  } else {
    hipLaunchKernelGGL(seggps_direct, dim3(8192 / 4), dim3(256), 0, stream,
                       indices, eps, out);
  }
}